// Round 4
// baseline (794.260 us; speedup 1.0000x reference)
//
#include <hip/hip_runtime.h>
#include <stdint.h>

typedef __attribute__((ext_vector_type(8))) short short8;
typedef __attribute__((ext_vector_type(4))) float floatx4;

static inline size_t align256(size_t x) { return (x + 255) & ~size_t(255); }

__device__ __forceinline__ unsigned short f2bf(float f) {
    unsigned u = __float_as_uint(f);
    u += 0x7fff + ((u >> 16) & 1);     // round-to-nearest-even
    return (unsigned short)(u >> 16);
}
__device__ __forceinline__ unsigned pack_bf16(float a, float b) {
    return (unsigned)f2bf(a) | ((unsigned)f2bf(b) << 16);
}
__device__ __forceinline__ float bf_lo(unsigned u) { return __uint_as_float(u << 16); }
__device__ __forceinline__ float bf_hi(unsigned u) { return __uint_as_float(u & 0xffff0000u); }

#define BSHIFT 7   // 128 nodes per dst-bucket

// ---- edge dtype detection: is the edge_index buffer int32 or int64? ----
__global__ void k_detect(const long long* __restrict__ e, int n_check, int* __restrict__ is32) {
    int i = blockIdx.x * blockDim.x + threadIdx.x;
    if (i < n_check) {
        long long v = e[i];
        if (v < 0 || v > 0x7fffffffLL) atomicOr(is32, 1);
    }
}

// ---- count in-degree on dst + bucket histogram ----
__global__ void k_count(const void* __restrict__ eidx, int E, const int* __restrict__ is32,
                        int* __restrict__ counts, int* __restrict__ bcnt) {
    int e = blockIdx.x * blockDim.x + threadIdx.x;
    if (e >= E) return;
    int d;
    if (*is32) d = ((const int*)eidx)[(size_t)E + e];
    else       d = (int)((const long long*)eidx)[(size_t)E + e];
    atomicAdd(&counts[d], 1);
    atomicAdd(&bcnt[d >> BSHIFT], 1);
}

// ---- single-block exclusive scan of bucket counts -> bpos ----
__global__ __launch_bounds__(1024) void k_bscan(const int* __restrict__ bcnt,
                                                int* __restrict__ bpos, int nb) {
    __shared__ int swt[16];
    __shared__ int swt2[16];
    const int t = threadIdx.x, lane = t & 63, w = t >> 6;
    int carry = 0;
    for (int base = 0; base < nb; base += 1024) {
        int i = base + t;
        int v = (i < nb) ? bcnt[i] : 0;
        int incl = v;
        #pragma unroll
        for (int off = 1; off < 64; off <<= 1) {
            int nbr = __shfl_up(incl, off, 64);
            if (lane >= off) incl += nbr;
        }
        if (lane == 63) swt[w] = incl;
        __syncthreads();
        if (w == 0) {
            int wincl = (lane < 16) ? swt[lane] : 0;
            #pragma unroll
            for (int off = 1; off < 16; off <<= 1) {
                int nbr = __shfl_up(wincl, off, 64);
                if (lane >= off) wincl += nbr;
            }
            if (lane < 16) swt2[lane] = wincl;
        }
        __syncthreads();
        int excl = carry + ((w == 0) ? 0 : swt2[w - 1]) + incl - v;
        if (i < nb) bpos[i] = excl;
        carry += swt2[15];
        __syncthreads();
    }
}

// ---- hierarchical exclusive scan of counts: pass 1 ----
__global__ __launch_bounds__(1024) void k_scan1(const int* __restrict__ counts,
                                                int* __restrict__ row_start,
                                                int* __restrict__ bsum, int N) {
    __shared__ int swt[16];
    __shared__ int swt2[16];
    const int t = threadIdx.x, lane = t & 63, w = t >> 6;
    int i = blockIdx.x * 1024 + t;
    int v = (i < N) ? counts[i] : 0;
    int incl = v;
    #pragma unroll
    for (int off = 1; off < 64; off <<= 1) {
        int nbr = __shfl_up(incl, off, 64);
        if (lane >= off) incl += nbr;
    }
    if (lane == 63) swt[w] = incl;
    __syncthreads();
    if (w == 0) {
        int wincl = (lane < 16) ? swt[lane] : 0;
        #pragma unroll
        for (int off = 1; off < 16; off <<= 1) {
            int nbr = __shfl_up(wincl, off, 64);
            if (lane >= off) wincl += nbr;
        }
        if (lane < 16) swt2[lane] = wincl;
    }
    __syncthreads();
    int excl = ((w == 0) ? 0 : swt2[w - 1]) + incl - v;
    if (i < N) row_start[i] = excl;
    if (t == 0) bsum[blockIdx.x] = swt2[15];
}

// ---- pass 2: single-block scan of block sums ----
__global__ __launch_bounds__(1024) void k_scan2(const int* __restrict__ bsum,
                                                int* __restrict__ bexc,
                                                int* __restrict__ row_start,
                                                int nblk, int N) {
    __shared__ int swt[16];
    __shared__ int swt2[16];
    const int t = threadIdx.x, lane = t & 63, w = t >> 6;
    int carry = 0;
    for (int base = 0; base < nblk; base += 1024) {
        int i = base + t;
        int v = (i < nblk) ? bsum[i] : 0;
        int incl = v;
        #pragma unroll
        for (int off = 1; off < 64; off <<= 1) {
            int nbr = __shfl_up(incl, off, 64);
            if (lane >= off) incl += nbr;
        }
        if (lane == 63) swt[w] = incl;
        __syncthreads();
        if (w == 0) {
            int wincl = (lane < 16) ? swt[lane] : 0;
            #pragma unroll
            for (int off = 1; off < 16; off <<= 1) {
                int nbr = __shfl_up(wincl, off, 64);
                if (lane >= off) wincl += nbr;
            }
            if (lane < 16) swt2[lane] = wincl;
        }
        __syncthreads();
        int excl = carry + ((w == 0) ? 0 : swt2[w - 1]) + incl - v;
        if (i < nblk) bexc[i] = excl;
        carry += swt2[15];
        __syncthreads();
    }
    if (t == 0) row_start[N] = carry;
}

// ---- pass 3: add block offsets; init pos; compute dinv ----
__global__ void k_scan3(int* __restrict__ row_start, int* __restrict__ pos,
                        const int* __restrict__ bexc, const int* __restrict__ counts,
                        float* __restrict__ dinv, int N) {
    int i = blockIdx.x * blockDim.x + threadIdx.x;
    if (i < N) {
        int r = row_start[i] + bexc[i >> 10];
        row_start[i] = r;
        pos[i] = r;
        dinv[i] = rsqrtf((float)counts[i] + 1.0f);
    }
}

// ---- binned fill pass A: append (src,dst) into dst-buckets ----
__global__ void k_bfill(const void* __restrict__ eidx, int E, const int* __restrict__ is32,
                        int* __restrict__ bpos, uint2* __restrict__ bbuf) {
    int e = blockIdx.x * blockDim.x + threadIdx.x;
    if (e >= E) return;
    int s, d;
    if (*is32) {
        s = ((const int*)eidx)[e];
        d = ((const int*)eidx)[(size_t)E + e];
    } else {
        s = (int)((const long long*)eidx)[e];
        d = (int)((const long long*)eidx)[(size_t)E + e];
    }
    int slot = atomicAdd(&bpos[d >> BSHIFT], 1);
    bbuf[slot] = make_uint2((unsigned)s, (unsigned)d);
}

// ---- binned fill pass B: scatter within bucket (L1/L2-local) ----
__global__ void k_fill2(const uint2* __restrict__ bbuf, int E,
                        int* __restrict__ pos, int* __restrict__ esrc) {
    int i = blockIdx.x * blockDim.x + threadIdx.x;
    if (i >= E) return;
    uint2 sd = bbuf[i];
    int p = atomicAdd(&pos[sd.y], 1);
    esrc[p] = (int)sd.x;
}

// ---- fp32 -> bf16 conversion, 8 elems/thread ----
__global__ void k_cvt8(const float* __restrict__ in, unsigned short* __restrict__ out, int n8) {
    int i = blockIdx.x * blockDim.x + threadIdx.x;
    if (i >= n8) return;
    float4 a = ((const float4*)in)[2 * i];
    float4 b = ((const float4*)in)[2 * i + 1];
    uint4 o;
    o.x = pack_bf16(a.x, a.y); o.y = pack_bf16(a.z, a.w);
    o.z = pack_bf16(b.x, b.y); o.w = pack_bf16(b.z, b.w);
    ((uint4*)out)[i] = o;
}

// ---- W [K][M] fp32 -> Wt [M][K] bf16 (transpose + convert; tiny) ----
__global__ void k_cvt_wt(const float* __restrict__ W, unsigned short* __restrict__ Wt,
                         int K, int M) {
    int idx = blockIdx.x * blockDim.x + threadIdx.x;
    if (idx >= K * M) return;
    int k = idx / M, n = idx % M;
    Wt[(size_t)n * K + k] = f2bf(W[idx]);
}

// ---- bf16 MFMA GEMM: C[N x M](bf16) = A[N x 128](bf16) @ Bt[M x 128](bf16)^T ----
// Block: 256 thr (4 waves), tile 64 rows x 64 cols, K=128 in one LDS stage.
// MFMA 16x16x32 layouts (verified m89/m91/m120):
//   A-frag:  lane holds A[m=lane&15][k=quad*8+j]
//   B-frag:  lane holds B[k=quad*8+j][n=lane&15]   (rows of Bt)
//   C/D:     lane,reg -> D[row=quad*4+reg][col=lane&15]
__global__ __launch_bounds__(256, 4) void k_gemm_mfma(
        const unsigned short* __restrict__ A,
        const unsigned short* __restrict__ Bt,
        unsigned short* __restrict__ C,
        int N, int M) {
    constexpr int LD = 136;               // 128 + 8 u16 pad: 2-way LDS aliasing = free
    __shared__ unsigned short As[64 * LD];
    __shared__ unsigned short Bs[64 * LD];
    const int tid = threadIdx.x;
    const int wave = tid >> 6, lane = tid & 63;
    const int q = lane >> 4, tm = lane & 15;
    const int row0 = blockIdx.x * 64;
    const int c0 = blockIdx.y * 64;

    {   // stage A rows [row0,row0+64) and Bt rows [c0,c0+64): 1024 uint4 each
        const uint4* Ag = (const uint4*)A;
        const uint4* Bg = (const uint4*)Bt;
        #pragma unroll
        for (int it = 0; it < 4; ++it) {
            int i = tid + it * 256;
            int r = i >> 4, o = i & 15;
            int row = row0 + r;
            uint4 v = make_uint4(0, 0, 0, 0);
            if (row < N) v = Ag[(size_t)row * 16 + o];
            *(uint4*)&As[r * LD + o * 8] = v;
            *(uint4*)&Bs[r * LD + o * 8] = Bg[(size_t)(c0 + r) * 16 + o];
        }
    }
    __syncthreads();

    floatx4 acc[4];
    #pragma unroll
    for (int g = 0; g < 4; ++g) acc[g] = (floatx4){0.f, 0.f, 0.f, 0.f};

    const int arow = wave * 16 + tm;
    #pragma unroll
    for (int kc = 0; kc < 4; ++kc) {
        short8 af = *(const short8*)&As[arow * LD + kc * 32 + q * 8];
        #pragma unroll
        for (int g = 0; g < 4; ++g) {
            short8 bf = *(const short8*)&Bs[(g * 16 + tm) * LD + kc * 32 + q * 8];
            acc[g] = __builtin_amdgcn_mfma_f32_16x16x32_bf16(af, bf, acc[g], 0, 0, 0);
        }
    }

    #pragma unroll
    for (int g = 0; g < 4; ++g) {
        #pragma unroll
        for (int r = 0; r < 4; ++r) {
            int row = row0 + wave * 16 + q * 4 + r;
            if (row < N) C[(size_t)row * M + c0 + g * 16 + tm] = f2bf(acc[g][r]);
        }
    }
}

// ---- aggregation, F=128, bf16 in, bf16 out (+bias+ReLU); one wave per node ----
__global__ __launch_bounds__(256) void k_agg128(const unsigned* __restrict__ Hb,
        const float* __restrict__ dinv, const int* __restrict__ rs,
        const int* __restrict__ esrc, const float* __restrict__ bias,
        unsigned* __restrict__ out, int N) {
    int wid = (blockIdx.x * 256 + threadIdx.x) >> 6;
    if (wid >= N) return;
    int l = threadIdx.x & 63;
    float di = dinv[wid];
    unsigned a = Hb[(size_t)wid * 64 + l];
    float accx = di * bf_lo(a), accy = di * bf_hi(a);
    int k = rs[wid], kend = rs[wid + 1];
    for (; k + 4 <= kend; k += 4) {
        int sA = esrc[k], sB = esrc[k + 1], sC = esrc[k + 2], sD = esrc[k + 3];
        float wA = dinv[sA], wB = dinv[sB], wC = dinv[sC], wD = dinv[sD];
        unsigned gA = Hb[(size_t)sA * 64 + l];
        unsigned gB = Hb[(size_t)sB * 64 + l];
        unsigned gC = Hb[(size_t)sC * 64 + l];
        unsigned gD = Hb[(size_t)sD * 64 + l];
        accx = fmaf(wA, bf_lo(gA), accx); accy = fmaf(wA, bf_hi(gA), accy);
        accx = fmaf(wB, bf_lo(gB), accx); accy = fmaf(wB, bf_hi(gB), accy);
        accx = fmaf(wC, bf_lo(gC), accx); accy = fmaf(wC, bf_hi(gC), accy);
        accx = fmaf(wD, bf_lo(gD), accx); accy = fmaf(wD, bf_hi(gD), accy);
    }
    for (; k < kend; ++k) {
        int s = esrc[k];
        float w = dinv[s];
        unsigned g = Hb[(size_t)s * 64 + l];
        accx = fmaf(w, bf_lo(g), accx);
        accy = fmaf(w, bf_hi(g), accy);
    }
    float2 b = ((const float2*)bias)[l];
    float ox = fmaxf(fmaf(di, accx, b.x), 0.f);   // layer 1: ReLU
    float oy = fmaxf(fmaf(di, accy, b.y), 0.f);
    out[(size_t)wid * 64 + l] = pack_bf16(ox, oy);
}

// ---- aggregation, F=64, bf16 in, fp32 out (+bias); one wave per node ----
__global__ __launch_bounds__(256) void k_agg64(const unsigned short* __restrict__ Hb,
        const float* __restrict__ dinv, const int* __restrict__ rs,
        const int* __restrict__ esrc, const float* __restrict__ bias,
        float* __restrict__ out, int N) {
    int wid = (blockIdx.x * 256 + threadIdx.x) >> 6;
    if (wid >= N) return;
    int l = threadIdx.x & 63;
    float di = dinv[wid];
    float acc = di * __uint_as_float((unsigned)Hb[(size_t)wid * 64 + l] << 16);
    int k = rs[wid], kend = rs[wid + 1];
    for (; k + 4 <= kend; k += 4) {
        int sA = esrc[k], sB = esrc[k + 1], sC = esrc[k + 2], sD = esrc[k + 3];
        float wA = dinv[sA], wB = dinv[sB], wC = dinv[sC], wD = dinv[sD];
        float gA = __uint_as_float((unsigned)Hb[(size_t)sA * 64 + l] << 16);
        float gB = __uint_as_float((unsigned)Hb[(size_t)sB * 64 + l] << 16);
        float gC = __uint_as_float((unsigned)Hb[(size_t)sC * 64 + l] << 16);
        float gD = __uint_as_float((unsigned)Hb[(size_t)sD * 64 + l] << 16);
        acc = fmaf(wA, gA, acc); acc = fmaf(wB, gB, acc);
        acc = fmaf(wC, gC, acc); acc = fmaf(wD, gD, acc);
    }
    for (; k < kend; ++k) {
        int s = esrc[k];
        acc = fmaf(dinv[s], __uint_as_float((unsigned)Hb[(size_t)s * 64 + l] << 16), acc);
    }
    out[(size_t)wid * 64 + l] = fmaf(di, acc, bias[l]);
}

extern "C" void kernel_launch(void* const* d_in, const int* in_sizes, int n_in,
                              void* d_out, int out_size, void* d_ws, size_t ws_size,
                              hipStream_t stream) {
    const float* x  = (const float*)d_in[0];
    const void*  ei = d_in[1];
    const float* W1 = (const float*)d_in[2];
    const float* b1 = (const float*)d_in[3];
    const float* W2 = (const float*)d_in[4];
    const float* b2 = (const float*)d_in[5];

    const int HID = in_sizes[3];            // 128
    const int IN  = in_sizes[2] / HID;      // 128
    const int OUT = in_sizes[4] / HID;      // 64
    const int N   = in_sizes[0] / IN;       // 50000
    const int E   = in_sizes[1] / 2;        // 800000
    const int NBLK = (N + 1023) / 1024;
    const int NB   = (N + 127) >> BSHIFT;   // dst buckets

    char* p = (char*)d_ws;
    int* is32      = (int*)p;   p += 256;
    int* counts    = (int*)p;   p += align256((size_t)N * 4);
    int* bcnt      = (int*)p;   p += align256((size_t)NB * 4);
    size_t zero_bytes = (size_t)(p - (char*)d_ws);   // is32 + counts + bcnt
    int* bpos      = (int*)p;   p += align256((size_t)NB * 4);
    int* row_start = (int*)p;   p += align256((size_t)(N + 1) * 4);
    int* pos       = (int*)p;   p += align256((size_t)N * 4);
    int* bsum      = (int*)p;   p += align256((size_t)NBLK * 4);
    int* bexc      = (int*)p;   p += align256((size_t)NBLK * 4);
    int* esrc      = (int*)p;   p += align256((size_t)E * 4);
    float* dinv    = (float*)p; p += align256((size_t)N * 4);
    unsigned short* w1t = (unsigned short*)p; p += align256((size_t)HID * IN * 2);
    unsigned short* w2t = (unsigned short*)p; p += align256((size_t)OUT * HID * 2);
    unsigned short* xb  = (unsigned short*)p; p += align256((size_t)N * IN * 2);
    // bbuf (E uint2, dead after k_fill2) overlays hb (N*HID bf16, written later)
    size_t hb_bytes = (size_t)N * HID * 2, bbuf_bytes = (size_t)E * 8;
    uint2* bbuf    = (uint2*)p;
    unsigned short* hb = (unsigned short*)p;
    p += align256(hb_bytes > bbuf_bytes ? hb_bytes : bbuf_bytes);
    unsigned short* h1b = (unsigned short*)p; p += align256((size_t)N * HID * 2);
    unsigned short* h2b = (unsigned short*)p; p += align256((size_t)N * OUT * 2);

    hipMemsetAsync(d_ws, 0, zero_bytes, stream);

    k_detect<<<4, 256, 0, stream>>>((const long long*)ei, 1024, is32);
    k_count<<<(E + 255) / 256, 256, 0, stream>>>(ei, E, is32, counts, bcnt);
    k_bscan<<<1, 1024, 0, stream>>>(bcnt, bpos, NB);
    k_scan1<<<NBLK, 1024, 0, stream>>>(counts, row_start, bsum, N);
    k_scan2<<<1, 1024, 0, stream>>>(bsum, bexc, row_start, NBLK, N);
    k_scan3<<<(N + 255) / 256, 256, 0, stream>>>(row_start, pos, bexc, counts, dinv, N);
    k_bfill<<<(E + 255) / 256, 256, 0, stream>>>(ei, E, is32, bpos, bbuf);
    k_fill2<<<(E + 255) / 256, 256, 0, stream>>>(bbuf, E, pos, esrc);

    // bf16 conversions
    k_cvt8<<<((N * IN / 8) + 255) / 256, 256, 0, stream>>>(x, xb, N * IN / 8);
    k_cvt_wt<<<(IN * HID + 255) / 256, 256, 0, stream>>>(W1, w1t, IN, HID);
    k_cvt_wt<<<(HID * OUT + 255) / 256, 256, 0, stream>>>(W2, w2t, HID, OUT);

    // layer 1: hb = bf16(xb @ W1) ; h1b = bf16(relu(agg(hb) + b1))
    k_gemm_mfma<<<dim3((N + 63) / 64, HID / 64), 256, 0, stream>>>(xb, w1t, hb, N, HID);
    k_agg128<<<(N + 3) / 4, 256, 0, stream>>>((unsigned*)hb, dinv, row_start, esrc, b1,
                                              (unsigned*)h1b, N);

    // layer 2: h2b = bf16(h1b @ W2) ; out = agg(h2b) + b2
    k_gemm_mfma<<<dim3((N + 63) / 64, OUT / 64), 256, 0, stream>>>(h1b, w2t, h2b, N, OUT);
    k_agg64<<<(N + 3) / 4, 256, 0, stream>>>(h2b, dinv, row_start, esrc, b2, (float*)d_out, N);
}

// Round 5
// 294.049 us; speedup vs baseline: 2.7011x; 2.7011x over previous
//
#include <hip/hip_runtime.h>
#include <stdint.h>

typedef __attribute__((ext_vector_type(8))) short short8;
typedef __attribute__((ext_vector_type(4))) float floatx4;

static inline size_t align256(size_t x) { return (x + 255) & ~size_t(255); }

__device__ __forceinline__ unsigned short f2bf(float f) {
    unsigned u = __float_as_uint(f);
    u += 0x7fff + ((u >> 16) & 1);     // round-to-nearest-even
    return (unsigned short)(u >> 16);
}
__device__ __forceinline__ unsigned pack_bf16(float a, float b) {
    return (unsigned)f2bf(a) | ((unsigned)f2bf(b) << 16);
}
__device__ __forceinline__ float bf_lo(unsigned u) { return __uint_as_float(u << 16); }
__device__ __forceinline__ float bf_hi(unsigned u) { return __uint_as_float(u & 0xffff0000u); }

#define BSHIFT 7     // 128 nodes per dst-bucket
#define NBMAX 1024   // max buckets handled per LDS window
#define BFILL_CH 16384

// ---- edge dtype detection: is the edge_index buffer int32 or int64? ----
__global__ void k_detect(const long long* __restrict__ e, int n_check, int* __restrict__ is32) {
    int i = blockIdx.x * blockDim.x + threadIdx.x;
    if (i < n_check) {
        long long v = e[i];
        if (v < 0 || v > 0x7fffffffLL) atomicOr(is32, 1);
    }
}

// ---- count in-degree on dst (50k addresses: low contention — do NOT add
//      coarser-granularity atomics here; 391-address histogram cost 305 us) ----
__global__ void k_count(const void* __restrict__ eidx, int E, const int* __restrict__ is32,
                        int* __restrict__ counts) {
    int e = blockIdx.x * blockDim.x + threadIdx.x;
    if (e >= E) return;
    int d;
    if (*is32) d = ((const int*)eidx)[(size_t)E + e];
    else       d = (int)((const long long*)eidx)[(size_t)E + e];
    atomicAdd(&counts[d], 1);
}

// ---- hierarchical exclusive scan of counts: pass 1 ----
__global__ __launch_bounds__(1024) void k_scan1(const int* __restrict__ counts,
                                                int* __restrict__ row_start,
                                                int* __restrict__ bsum, int N) {
    __shared__ int swt[16];
    __shared__ int swt2[16];
    const int t = threadIdx.x, lane = t & 63, w = t >> 6;
    int i = blockIdx.x * 1024 + t;
    int v = (i < N) ? counts[i] : 0;
    int incl = v;
    #pragma unroll
    for (int off = 1; off < 64; off <<= 1) {
        int nbr = __shfl_up(incl, off, 64);
        if (lane >= off) incl += nbr;
    }
    if (lane == 63) swt[w] = incl;
    __syncthreads();
    if (w == 0) {
        int wincl = (lane < 16) ? swt[lane] : 0;
        #pragma unroll
        for (int off = 1; off < 16; off <<= 1) {
            int nbr = __shfl_up(wincl, off, 64);
            if (lane >= off) wincl += nbr;
        }
        if (lane < 16) swt2[lane] = wincl;
    }
    __syncthreads();
    int excl = ((w == 0) ? 0 : swt2[w - 1]) + incl - v;
    if (i < N) row_start[i] = excl;
    if (t == 0) bsum[blockIdx.x] = swt2[15];
}

// ---- pass 2: single-block scan of block sums ----
__global__ __launch_bounds__(1024) void k_scan2(const int* __restrict__ bsum,
                                                int* __restrict__ bexc,
                                                int* __restrict__ row_start,
                                                int nblk, int N) {
    __shared__ int swt[16];
    __shared__ int swt2[16];
    const int t = threadIdx.x, lane = t & 63, w = t >> 6;
    int carry = 0;
    for (int base = 0; base < nblk; base += 1024) {
        int i = base + t;
        int v = (i < nblk) ? bsum[i] : 0;
        int incl = v;
        #pragma unroll
        for (int off = 1; off < 64; off <<= 1) {
            int nbr = __shfl_up(incl, off, 64);
            if (lane >= off) incl += nbr;
        }
        if (lane == 63) swt[w] = incl;
        __syncthreads();
        if (w == 0) {
            int wincl = (lane < 16) ? swt[lane] : 0;
            #pragma unroll
            for (int off = 1; off < 16; off <<= 1) {
                int nbr = __shfl_up(wincl, off, 64);
                if (lane >= off) wincl += nbr;
            }
            if (lane < 16) swt2[lane] = wincl;
        }
        __syncthreads();
        int excl = carry + ((w == 0) ? 0 : swt2[w - 1]) + incl - v;
        if (i < nblk) bexc[i] = excl;
        carry += swt2[15];
        __syncthreads();
    }
    if (t == 0) row_start[N] = carry;
}

// ---- pass 3: add block offsets; init pos; compute dinv ----
__global__ void k_scan3(int* __restrict__ row_start, int* __restrict__ pos,
                        const int* __restrict__ bexc, const int* __restrict__ counts,
                        float* __restrict__ dinv, int N) {
    int i = blockIdx.x * blockDim.x + threadIdx.x;
    if (i < N) {
        int r = row_start[i] + bexc[i >> 10];
        row_start[i] = r;
        pos[i] = r;
        dinv[i] = rsqrtf((float)counts[i] + 1.0f);
    }
}

// ---- bucket base offsets: free from row_start (CSR is dst-sorted, buckets
//      are contiguous dst ranges) ----
__global__ void k_binit(const int* __restrict__ row_start, int* __restrict__ bpos,
                        int NB, int N) {
    int b = blockIdx.x * blockDim.x + threadIdx.x;
    if (b < NB) {
        int node = b << BSHIFT;
        bpos[b] = row_start[node > N ? N : node];
    }
}

// ---- binned fill pass A: chunked LDS-histogram append into dst-buckets.
//      One global atomic per (block,bucket) — 49*391 ~= 19k total. ----
__global__ __launch_bounds__(256) void k_bfill(const void* __restrict__ eidx, int E,
                                               const int* __restrict__ is32,
                                               int* __restrict__ bpos,
                                               uint2* __restrict__ bbuf, int NB) {
    __shared__ int hist[NBMAX];
    __shared__ int base[NBMAX];
    __shared__ int rank[NBMAX];
    const int t = threadIdx.x;
    const int e0 = blockIdx.x * BFILL_CH;
    const int e1 = (e0 + BFILL_CH < E) ? e0 + BFILL_CH : E;
    const bool i32 = (*is32) != 0;
    const int* e32 = (const int*)eidx;
    const long long* e64 = (const long long*)eidx;

    for (int b0 = 0; b0 < NB; b0 += NBMAX) {
        int bw = (NB - b0 < NBMAX) ? NB - b0 : NBMAX;
        for (int i = t; i < bw; i += 256) { hist[i] = 0; rank[i] = 0; }
        __syncthreads();
        // phase 1: chunk histogram (LDS atomics)
        for (int e = e0 + t; e < e1; e += 256) {
            int d = i32 ? e32[(size_t)E + e] : (int)e64[(size_t)E + e];
            int b = (d >> BSHIFT) - b0;
            if (b >= 0 && b < bw) atomicAdd(&hist[b], 1);
        }
        __syncthreads();
        // phase 2: reserve bucket space (one global atomic per nonzero bucket)
        for (int i = t; i < bw; i += 256) {
            int h = hist[i];
            base[i] = h ? atomicAdd(&bpos[b0 + i], h) : 0;
        }
        __syncthreads();
        // phase 3: re-read chunk, rank within block, write contiguous runs
        for (int e = e0 + t; e < e1; e += 256) {
            int s, d;
            if (i32) { s = e32[e]; d = e32[(size_t)E + e]; }
            else     { s = (int)e64[e]; d = (int)e64[(size_t)E + e]; }
            int b = (d >> BSHIFT) - b0;
            if (b >= 0 && b < bw) {
                int slot = base[b] + atomicAdd(&rank[b], 1);
                bbuf[slot] = make_uint2((unsigned)s, (unsigned)d);
            }
        }
        __syncthreads();
    }
}

// ---- binned fill pass B: scatter within bucket (~8KB window, cache-local) ----
__global__ void k_fill2(const uint2* __restrict__ bbuf, int E,
                        int* __restrict__ pos, int* __restrict__ esrc) {
    int i = blockIdx.x * blockDim.x + threadIdx.x;
    if (i >= E) return;
    uint2 sd = bbuf[i];
    int p = atomicAdd(&pos[sd.y], 1);
    esrc[p] = (int)sd.x;
}

// ---- fp32 -> bf16 conversion, 8 elems/thread ----
__global__ void k_cvt8(const float* __restrict__ in, unsigned short* __restrict__ out, int n8) {
    int i = blockIdx.x * blockDim.x + threadIdx.x;
    if (i >= n8) return;
    float4 a = ((const float4*)in)[2 * i];
    float4 b = ((const float4*)in)[2 * i + 1];
    uint4 o;
    o.x = pack_bf16(a.x, a.y); o.y = pack_bf16(a.z, a.w);
    o.z = pack_bf16(b.x, b.y); o.w = pack_bf16(b.z, b.w);
    ((uint4*)out)[i] = o;
}

// ---- W [K][M] fp32 -> Wt [M][K] bf16 (transpose + convert; tiny) ----
__global__ void k_cvt_wt(const float* __restrict__ W, unsigned short* __restrict__ Wt,
                         int K, int M) {
    int idx = blockIdx.x * blockDim.x + threadIdx.x;
    if (idx >= K * M) return;
    int k = idx / M, n = idx % M;
    Wt[(size_t)n * K + k] = f2bf(W[idx]);
}

// ---- bf16 MFMA GEMM: C[N x M](bf16) = A[N x 128](bf16) @ Bt[M x 128](bf16)^T ----
// Block: 256 thr (4 waves), tile 64 rows x 64 cols, K=128 in one LDS stage.
// MFMA 16x16x32 layouts (verified m89/m91/m120):
//   A-frag:  lane holds A[m=lane&15][k=quad*8+j]
//   B-frag:  lane holds B[k=quad*8+j][n=lane&15]   (rows of Bt)
//   C/D:     lane,reg -> D[row=quad*4+reg][col=lane&15]
__global__ __launch_bounds__(256, 4) void k_gemm_mfma(
        const unsigned short* __restrict__ A,
        const unsigned short* __restrict__ Bt,
        unsigned short* __restrict__ C,
        int N, int M) {
    constexpr int LD = 136;               // 128 + 8 u16 pad: 2-way LDS aliasing = free
    __shared__ unsigned short As[64 * LD];
    __shared__ unsigned short Bs[64 * LD];
    const int tid = threadIdx.x;
    const int wave = tid >> 6, lane = tid & 63;
    const int q = lane >> 4, tm = lane & 15;
    const int row0 = blockIdx.x * 64;
    const int c0 = blockIdx.y * 64;

    {   // stage A rows [row0,row0+64) and Bt rows [c0,c0+64): 1024 uint4 each
        const uint4* Ag = (const uint4*)A;
        const uint4* Bg = (const uint4*)Bt;
        #pragma unroll
        for (int it = 0; it < 4; ++it) {
            int i = tid + it * 256;
            int r = i >> 4, o = i & 15;
            int row = row0 + r;
            uint4 v = make_uint4(0, 0, 0, 0);
            if (row < N) v = Ag[(size_t)row * 16 + o];
            *(uint4*)&As[r * LD + o * 8] = v;
            *(uint4*)&Bs[r * LD + o * 8] = Bg[(size_t)(c0 + r) * 16 + o];
        }
    }
    __syncthreads();

    floatx4 acc[4];
    #pragma unroll
    for (int g = 0; g < 4; ++g) acc[g] = (floatx4){0.f, 0.f, 0.f, 0.f};

    const int arow = wave * 16 + tm;
    #pragma unroll
    for (int kc = 0; kc < 4; ++kc) {
        short8 af = *(const short8*)&As[arow * LD + kc * 32 + q * 8];
        #pragma unroll
        for (int g = 0; g < 4; ++g) {
            short8 bf = *(const short8*)&Bs[(g * 16 + tm) * LD + kc * 32 + q * 8];
            acc[g] = __builtin_amdgcn_mfma_f32_16x16x32_bf16(af, bf, acc[g], 0, 0, 0);
        }
    }

    #pragma unroll
    for (int g = 0; g < 4; ++g) {
        #pragma unroll
        for (int r = 0; r < 4; ++r) {
            int row = row0 + wave * 16 + q * 4 + r;
            if (row < N) C[(size_t)row * M + c0 + g * 16 + tm] = f2bf(acc[g][r]);
        }
    }
}

// ---- aggregation, F=128, bf16 in, bf16 out (+bias+ReLU); one wave per node ----
__global__ __launch_bounds__(256) void k_agg128(const unsigned* __restrict__ Hb,
        const float* __restrict__ dinv, const int* __restrict__ rs,
        const int* __restrict__ esrc, const float* __restrict__ bias,
        unsigned* __restrict__ out, int N) {
    int wid = (blockIdx.x * 256 + threadIdx.x) >> 6;
    if (wid >= N) return;
    int l = threadIdx.x & 63;
    float di = dinv[wid];
    unsigned a = Hb[(size_t)wid * 64 + l];
    float accx = di * bf_lo(a), accy = di * bf_hi(a);
    int k = rs[wid], kend = rs[wid + 1];
    for (; k + 4 <= kend; k += 4) {
        int sA = esrc[k], sB = esrc[k + 1], sC = esrc[k + 2], sD = esrc[k + 3];
        float wA = dinv[sA], wB = dinv[sB], wC = dinv[sC], wD = dinv[sD];
        unsigned gA = Hb[(size_t)sA * 64 + l];
        unsigned gB = Hb[(size_t)sB * 64 + l];
        unsigned gC = Hb[(size_t)sC * 64 + l];
        unsigned gD = Hb[(size_t)sD * 64 + l];
        accx = fmaf(wA, bf_lo(gA), accx); accy = fmaf(wA, bf_hi(gA), accy);
        accx = fmaf(wB, bf_lo(gB), accx); accy = fmaf(wB, bf_hi(gB), accy);
        accx = fmaf(wC, bf_lo(gC), accx); accy = fmaf(wC, bf_hi(gC), accy);
        accx = fmaf(wD, bf_lo(gD), accx); accy = fmaf(wD, bf_hi(gD), accy);
    }
    for (; k < kend; ++k) {
        int s = esrc[k];
        float w = dinv[s];
        unsigned g = Hb[(size_t)s * 64 + l];
        accx = fmaf(w, bf_lo(g), accx);
        accy = fmaf(w, bf_hi(g), accy);
    }
    float2 b = ((const float2*)bias)[l];
    float ox = fmaxf(fmaf(di, accx, b.x), 0.f);   // layer 1: ReLU
    float oy = fmaxf(fmaf(di, accy, b.y), 0.f);
    out[(size_t)wid * 64 + l] = pack_bf16(ox, oy);
}

// ---- aggregation, F=64, bf16 in, fp32 out (+bias); one wave per node ----
__global__ __launch_bounds__(256) void k_agg64(const unsigned short* __restrict__ Hb,
        const float* __restrict__ dinv, const int* __restrict__ rs,
        const int* __restrict__ esrc, const float* __restrict__ bias,
        float* __restrict__ out, int N) {
    int wid = (blockIdx.x * 256 + threadIdx.x) >> 6;
    if (wid >= N) return;
    int l = threadIdx.x & 63;
    float di = dinv[wid];
    float acc = di * __uint_as_float((unsigned)Hb[(size_t)wid * 64 + l] << 16);
    int k = rs[wid], kend = rs[wid + 1];
    for (; k + 4 <= kend; k += 4) {
        int sA = esrc[k], sB = esrc[k + 1], sC = esrc[k + 2], sD = esrc[k + 3];
        float wA = dinv[sA], wB = dinv[sB], wC = dinv[sC], wD = dinv[sD];
        float gA = __uint_as_float((unsigned)Hb[(size_t)sA * 64 + l] << 16);
        float gB = __uint_as_float((unsigned)Hb[(size_t)sB * 64 + l] << 16);
        float gC = __uint_as_float((unsigned)Hb[(size_t)sC * 64 + l] << 16);
        float gD = __uint_as_float((unsigned)Hb[(size_t)sD * 64 + l] << 16);
        acc = fmaf(wA, gA, acc); acc = fmaf(wB, gB, acc);
        acc = fmaf(wC, gC, acc); acc = fmaf(wD, gD, acc);
    }
    for (; k < kend; ++k) {
        int s = esrc[k];
        acc = fmaf(dinv[s], __uint_as_float((unsigned)Hb[(size_t)s * 64 + l] << 16), acc);
    }
    out[(size_t)wid * 64 + l] = fmaf(di, acc, bias[l]);
}

extern "C" void kernel_launch(void* const* d_in, const int* in_sizes, int n_in,
                              void* d_out, int out_size, void* d_ws, size_t ws_size,
                              hipStream_t stream) {
    const float* x  = (const float*)d_in[0];
    const void*  ei = d_in[1];
    const float* W1 = (const float*)d_in[2];
    const float* b1 = (const float*)d_in[3];
    const float* W2 = (const float*)d_in[4];
    const float* b2 = (const float*)d_in[5];

    const int HID = in_sizes[3];            // 128
    const int IN  = in_sizes[2] / HID;      // 128
    const int OUT = in_sizes[4] / HID;      // 64
    const int N   = in_sizes[0] / IN;       // 50000
    const int E   = in_sizes[1] / 2;        // 800000
    const int NBLK = (N + 1023) / 1024;
    const int NB   = (N + 127) >> BSHIFT;   // dst buckets

    char* p = (char*)d_ws;
    int* is32      = (int*)p;   p += 256;
    int* counts    = (int*)p;   p += align256((size_t)N * 4);
    size_t zero_bytes = (size_t)(p - (char*)d_ws);   // is32 + counts
    int* bpos      = (int*)p;   p += align256((size_t)NB * 4);
    int* row_start = (int*)p;   p += align256((size_t)(N + 1) * 4);
    int* pos       = (int*)p;   p += align256((size_t)N * 4);
    int* bsum      = (int*)p;   p += align256((size_t)NBLK * 4);
    int* bexc      = (int*)p;   p += align256((size_t)NBLK * 4);
    int* esrc      = (int*)p;   p += align256((size_t)E * 4);
    float* dinv    = (float*)p; p += align256((size_t)N * 4);
    unsigned short* w1t = (unsigned short*)p; p += align256((size_t)HID * IN * 2);
    unsigned short* w2t = (unsigned short*)p; p += align256((size_t)OUT * HID * 2);
    unsigned short* xb  = (unsigned short*)p; p += align256((size_t)N * IN * 2);
    // bbuf (E uint2, dead after k_fill2) overlays hb (N*HID bf16, written later)
    size_t hb_bytes = (size_t)N * HID * 2, bbuf_bytes = (size_t)E * 8;
    uint2* bbuf    = (uint2*)p;
    unsigned short* hb = (unsigned short*)p;
    p += align256(hb_bytes > bbuf_bytes ? hb_bytes : bbuf_bytes);
    unsigned short* h1b = (unsigned short*)p; p += align256((size_t)N * HID * 2);
    unsigned short* h2b = (unsigned short*)p; p += align256((size_t)N * OUT * 2);

    hipMemsetAsync(d_ws, 0, zero_bytes, stream);

    k_detect<<<4, 256, 0, stream>>>((const long long*)ei, 1024, is32);
    k_count<<<(E + 255) / 256, 256, 0, stream>>>(ei, E, is32, counts);
    k_scan1<<<NBLK, 1024, 0, stream>>>(counts, row_start, bsum, N);
    k_scan2<<<1, 1024, 0, stream>>>(bsum, bexc, row_start, NBLK, N);
    k_scan3<<<(N + 255) / 256, 256, 0, stream>>>(row_start, pos, bexc, counts, dinv, N);
    k_binit<<<(NB + 255) / 256, 256, 0, stream>>>(row_start, bpos, NB, N);
    k_bfill<<<(E + BFILL_CH - 1) / BFILL_CH, 256, 0, stream>>>(ei, E, is32, bpos, bbuf, NB);
    k_fill2<<<(E + 255) / 256, 256, 0, stream>>>(bbuf, E, pos, esrc);

    // bf16 conversions
    k_cvt8<<<((N * IN / 8) + 255) / 256, 256, 0, stream>>>(x, xb, N * IN / 8);
    k_cvt_wt<<<(IN * HID + 255) / 256, 256, 0, stream>>>(W1, w1t, IN, HID);
    k_cvt_wt<<<(HID * OUT + 255) / 256, 256, 0, stream>>>(W2, w2t, HID, OUT);

    // layer 1: hb = bf16(xb @ W1) ; h1b = bf16(relu(agg(hb) + b1))
    k_gemm_mfma<<<dim3((N + 63) / 64, HID / 64), 256, 0, stream>>>(xb, w1t, hb, N, HID);
    k_agg128<<<(N + 3) / 4, 256, 0, stream>>>((unsigned*)hb, dinv, row_start, esrc, b1,
                                              (unsigned*)h1b, N);

    // layer 2: h2b = bf16(h1b @ W2) ; out = agg(h2b) + b2
    k_gemm_mfma<<<dim3((N + 63) / 64, OUT / 64), 256, 0, stream>>>(h1b, w2t, h2b, N, OUT);
    k_agg64<<<(N + 3) / 4, 256, 0, stream>>>(h2b, dinv, row_start, esrc, b2, (float*)d_out, N);
}

// Round 6
// 256.403 us; speedup vs baseline: 3.0977x; 1.1468x over previous
//
#include <hip/hip_runtime.h>
#include <stdint.h>

typedef __attribute__((ext_vector_type(8))) short short8;
typedef __attribute__((ext_vector_type(4))) float floatx4;

static inline size_t align256(size_t x) { return (x + 255) & ~size_t(255); }

__device__ __forceinline__ unsigned short f2bf(float f) {
    unsigned u = __float_as_uint(f);
    u += 0x7fff + ((u >> 16) & 1);     // round-to-nearest-even
    return (unsigned short)(u >> 16);
}
__device__ __forceinline__ unsigned pack_bf16(float a, float b) {
    return (unsigned)f2bf(a) | ((unsigned)f2bf(b) << 16);
}
__device__ __forceinline__ float bf_lo(unsigned u) { return __uint_as_float(u << 16); }
__device__ __forceinline__ float bf_hi(unsigned u) { return __uint_as_float(u & 0xffff0000u); }

#define BSHIFT 7     // 128 nodes per dst-bucket
#define NBMAX 1024   // max buckets per LDS window
#define CH 2048      // edges per chunk (391 chunks at E=800k -> full occupancy)

// ---- edge dtype detection: is the edge_index buffer int32 or int64? ----
__global__ void k_detect(const long long* __restrict__ e, int n_check, int* __restrict__ is32) {
    int i = blockIdx.x * blockDim.x + threadIdx.x;
    if (i < n_check) {
        long long v = e[i];
        if (v < 0 || v > 0x7fffffffLL) atomicOr(is32, 1);
    }
}

// ---- chunk histogram + global per-node counts (fused; one dst pass) ----
// chist layout: [bucket][chunk] (transposed for the per-bucket scan)
__global__ __launch_bounds__(256) void k_hist(const void* __restrict__ eidx, int E,
                                              const int* __restrict__ is32,
                                              int* __restrict__ counts,
                                              int* __restrict__ chist, int NB, int NC) {
    __shared__ int hist[NBMAX];
    const int t = threadIdx.x, c = blockIdx.x;
    const int e0 = c * CH;
    const int e1 = (e0 + CH < E) ? e0 + CH : E;
    const bool i32 = (*is32) != 0;
    const int* e32 = (const int*)eidx;
    const long long* e64 = (const long long*)eidx;
    for (int b0 = 0; b0 < NB; b0 += NBMAX) {
        int bw = (NB - b0 < NBMAX) ? NB - b0 : NBMAX;
        for (int i = t; i < bw; i += 256) hist[i] = 0;
        __syncthreads();
        for (int e = e0 + t; e < e1; e += 256) {
            int d = i32 ? e32[(size_t)E + e] : (int)e64[(size_t)E + e];
            if (b0 == 0) atomicAdd(&counts[d], 1);   // 50k addresses: low contention
            int b = (d >> BSHIFT) - b0;
            if (b >= 0 && b < bw) atomicAdd(&hist[b], 1);
        }
        __syncthreads();
        for (int i = t; i < bw; i += 256) chist[(size_t)(b0 + i) * NC + c] = hist[i];
        __syncthreads();
    }
}

// ---- hierarchical exclusive scan of counts: pass 1 ----
__global__ __launch_bounds__(1024) void k_scan1(const int* __restrict__ counts,
                                                int* __restrict__ row_start,
                                                int* __restrict__ bsum, int N) {
    __shared__ int swt[16];
    __shared__ int swt2[16];
    const int t = threadIdx.x, lane = t & 63, w = t >> 6;
    int i = blockIdx.x * 1024 + t;
    int v = (i < N) ? counts[i] : 0;
    int incl = v;
    #pragma unroll
    for (int off = 1; off < 64; off <<= 1) {
        int nbr = __shfl_up(incl, off, 64);
        if (lane >= off) incl += nbr;
    }
    if (lane == 63) swt[w] = incl;
    __syncthreads();
    if (w == 0) {
        int wincl = (lane < 16) ? swt[lane] : 0;
        #pragma unroll
        for (int off = 1; off < 16; off <<= 1) {
            int nbr = __shfl_up(wincl, off, 64);
            if (lane >= off) wincl += nbr;
        }
        if (lane < 16) swt2[lane] = wincl;
    }
    __syncthreads();
    int excl = ((w == 0) ? 0 : swt2[w - 1]) + incl - v;
    if (i < N) row_start[i] = excl;
    if (t == 0) bsum[blockIdx.x] = swt2[15];
}

// ---- pass 2: single-block scan of block sums ----
__global__ __launch_bounds__(1024) void k_scan2(const int* __restrict__ bsum,
                                                int* __restrict__ bexc,
                                                int* __restrict__ row_start,
                                                int nblk, int N) {
    __shared__ int swt[16];
    __shared__ int swt2[16];
    const int t = threadIdx.x, lane = t & 63, w = t >> 6;
    int carry = 0;
    for (int base = 0; base < nblk; base += 1024) {
        int i = base + t;
        int v = (i < nblk) ? bsum[i] : 0;
        int incl = v;
        #pragma unroll
        for (int off = 1; off < 64; off <<= 1) {
            int nbr = __shfl_up(incl, off, 64);
            if (lane >= off) incl += nbr;
        }
        if (lane == 63) swt[w] = incl;
        __syncthreads();
        if (w == 0) {
            int wincl = (lane < 16) ? swt[lane] : 0;
            #pragma unroll
            for (int off = 1; off < 16; off <<= 1) {
                int nbr = __shfl_up(wincl, off, 64);
                if (lane >= off) wincl += nbr;
            }
            if (lane < 16) swt2[lane] = wincl;
        }
        __syncthreads();
        int excl = carry + ((w == 0) ? 0 : swt2[w - 1]) + incl - v;
        if (i < nblk) bexc[i] = excl;
        carry += swt2[15];
        __syncthreads();
    }
    if (t == 0) row_start[N] = carry;
}

// ---- pass 3: add block offsets; init pos; compute dinv ----
__global__ void k_scan3(int* __restrict__ row_start, int* __restrict__ pos,
                        const int* __restrict__ bexc, const int* __restrict__ counts,
                        float* __restrict__ dinv, int N) {
    int i = blockIdx.x * blockDim.x + threadIdx.x;
    if (i < N) {
        int r = row_start[i] + bexc[i >> 10];
        row_start[i] = r;
        pos[i] = r;
        dinv[i] = rsqrtf((float)counts[i] + 1.0f);
    }
}

// ---- per-bucket scan over chunks: chist[b][c] -> global base offsets.
//      One wave per bucket; seeded from row_start (buckets = contiguous dst). ----
__global__ __launch_bounds__(256) void k_hscan(int* __restrict__ chist,
                                               const int* __restrict__ row_start,
                                               int NB, int NC) {
    int b = blockIdx.x * 4 + (threadIdx.x >> 6);
    if (b >= NB) return;
    int lane = threadIdx.x & 63;
    int* row = chist + (size_t)b * NC;
    int carry = row_start[b << BSHIFT];
    for (int base = 0; base < NC; base += 64) {
        int i = base + lane;
        int v = (i < NC) ? row[i] : 0;
        int incl = v;
        #pragma unroll
        for (int off = 1; off < 64; off <<= 1) {
            int nbr = __shfl_up(incl, off, 64);
            if (lane >= off) incl += nbr;
        }
        if (i < NC) row[i] = carry + incl - v;
        carry += __shfl(incl, 63, 64);
    }
}

// ---- binned fill: deterministic base + LDS rank; NO global atomics ----
__global__ __launch_bounds__(256) void k_bfill(const void* __restrict__ eidx, int E,
                                               const int* __restrict__ is32,
                                               const int* __restrict__ chist,
                                               uint2* __restrict__ bbuf, int NB, int NC) {
    __shared__ int rank[NBMAX];
    __shared__ int base[NBMAX];
    const int t = threadIdx.x, c = blockIdx.x;
    const int e0 = c * CH;
    const int e1 = (e0 + CH < E) ? e0 + CH : E;
    const bool i32 = (*is32) != 0;
    const int* e32 = (const int*)eidx;
    const long long* e64 = (const long long*)eidx;
    for (int b0 = 0; b0 < NB; b0 += NBMAX) {
        int bw = (NB - b0 < NBMAX) ? NB - b0 : NBMAX;
        for (int i = t; i < bw; i += 256) {
            rank[i] = 0;
            base[i] = chist[(size_t)(b0 + i) * NC + c];
        }
        __syncthreads();
        for (int e = e0 + t; e < e1; e += 256) {
            int s, d;
            if (i32) { s = e32[e]; d = e32[(size_t)E + e]; }
            else     { s = (int)e64[e]; d = (int)e64[(size_t)E + e]; }
            int b = (d >> BSHIFT) - b0;
            if (b >= 0 && b < bw) {
                int slot = base[b] + atomicAdd(&rank[b], 1);
                bbuf[slot] = make_uint2((unsigned)s, (unsigned)d);
            }
        }
        __syncthreads();
    }
}

// ---- fill pass B: scatter within bucket (~8KB window, cache-local) ----
__global__ void k_fill2(const uint2* __restrict__ bbuf, int E,
                        int* __restrict__ pos, int* __restrict__ esrc) {
    int i = blockIdx.x * blockDim.x + threadIdx.x;
    if (i >= E) return;
    uint2 sd = bbuf[i];
    int p = atomicAdd(&pos[sd.y], 1);
    esrc[p] = (int)sd.x;
}

// ---- fp32 -> bf16 conversion, 8 elems/thread ----
__global__ void k_cvt8(const float* __restrict__ in, unsigned short* __restrict__ out, int n8) {
    int i = blockIdx.x * blockDim.x + threadIdx.x;
    if (i >= n8) return;
    float4 a = ((const float4*)in)[2 * i];
    float4 b = ((const float4*)in)[2 * i + 1];
    uint4 o;
    o.x = pack_bf16(a.x, a.y); o.y = pack_bf16(a.z, a.w);
    o.z = pack_bf16(b.x, b.y); o.w = pack_bf16(b.z, b.w);
    ((uint4*)out)[i] = o;
}

// ---- both W [K][M] fp32 -> Wt [M][K] bf16 in one launch ----
__global__ void k_cvt_w(const float* __restrict__ W1, const float* __restrict__ W2,
                        unsigned short* __restrict__ w1t, unsigned short* __restrict__ w2t,
                        int K1, int M1, int K2, int M2) {
    int idx = blockIdx.x * blockDim.x + threadIdx.x;
    int n1 = K1 * M1;
    if (idx < n1) {
        int k = idx / M1, n = idx % M1;
        w1t[(size_t)n * K1 + k] = f2bf(W1[idx]);
    } else if (idx < n1 + K2 * M2) {
        int j = idx - n1;
        int k = j / M2, n = j % M2;
        w2t[(size_t)n * K2 + k] = f2bf(W2[j]);
    }
}

// ---- bf16 MFMA GEMM: C[N x M](bf16) = A[N x 128](bf16) @ Bt[M x 128](bf16)^T ----
// Block: 256 thr (4 waves), tile 64 rows x 64 cols, K=128 in one LDS stage.
__global__ __launch_bounds__(256, 4) void k_gemm_mfma(
        const unsigned short* __restrict__ A,
        const unsigned short* __restrict__ Bt,
        unsigned short* __restrict__ C,
        int N, int M) {
    constexpr int LD = 136;               // 128 + 8 u16 pad: 2-way LDS aliasing = free
    __shared__ unsigned short As[64 * LD];
    __shared__ unsigned short Bs[64 * LD];
    const int tid = threadIdx.x;
    const int wave = tid >> 6, lane = tid & 63;
    const int q = lane >> 4, tm = lane & 15;
    const int row0 = blockIdx.x * 64;
    const int c0 = blockIdx.y * 64;

    {
        const uint4* Ag = (const uint4*)A;
        const uint4* Bg = (const uint4*)Bt;
        #pragma unroll
        for (int it = 0; it < 4; ++it) {
            int i = tid + it * 256;
            int r = i >> 4, o = i & 15;
            int row = row0 + r;
            uint4 v = make_uint4(0, 0, 0, 0);
            if (row < N) v = Ag[(size_t)row * 16 + o];
            *(uint4*)&As[r * LD + o * 8] = v;
            *(uint4*)&Bs[r * LD + o * 8] = Bg[(size_t)(c0 + r) * 16 + o];
        }
    }
    __syncthreads();

    floatx4 acc[4];
    #pragma unroll
    for (int g = 0; g < 4; ++g) acc[g] = (floatx4){0.f, 0.f, 0.f, 0.f};

    const int arow = wave * 16 + tm;
    #pragma unroll
    for (int kc = 0; kc < 4; ++kc) {
        short8 af = *(const short8*)&As[arow * LD + kc * 32 + q * 8];
        #pragma unroll
        for (int g = 0; g < 4; ++g) {
            short8 bf = *(const short8*)&Bs[(g * 16 + tm) * LD + kc * 32 + q * 8];
            acc[g] = __builtin_amdgcn_mfma_f32_16x16x32_bf16(af, bf, acc[g], 0, 0, 0);
        }
    }

    #pragma unroll
    for (int g = 0; g < 4; ++g) {
        #pragma unroll
        for (int r = 0; r < 4; ++r) {
            int row = row0 + wave * 16 + q * 4 + r;
            if (row < N) C[(size_t)row * M + c0 + g * 16 + tm] = f2bf(acc[g][r]);
        }
    }
}

// ---- aggregation, F=128, bf16 in, bf16 out (+bias+ReLU); one wave per node ----
__global__ __launch_bounds__(256) void k_agg128(const unsigned* __restrict__ Hb,
        const float* __restrict__ dinv, const int* __restrict__ rs,
        const int* __restrict__ esrc, const float* __restrict__ bias,
        unsigned* __restrict__ out, int N) {
    int wid = (blockIdx.x * 256 + threadIdx.x) >> 6;
    if (wid >= N) return;
    int l = threadIdx.x & 63;
    float di = dinv[wid];
    unsigned a = Hb[(size_t)wid * 64 + l];
    float accx = di * bf_lo(a), accy = di * bf_hi(a);
    int k = rs[wid], kend = rs[wid + 1];
    for (; k + 4 <= kend; k += 4) {
        int sA = esrc[k], sB = esrc[k + 1], sC = esrc[k + 2], sD = esrc[k + 3];
        float wA = dinv[sA], wB = dinv[sB], wC = dinv[sC], wD = dinv[sD];
        unsigned gA = Hb[(size_t)sA * 64 + l];
        unsigned gB = Hb[(size_t)sB * 64 + l];
        unsigned gC = Hb[(size_t)sC * 64 + l];
        unsigned gD = Hb[(size_t)sD * 64 + l];
        accx = fmaf(wA, bf_lo(gA), accx); accy = fmaf(wA, bf_hi(gA), accy);
        accx = fmaf(wB, bf_lo(gB), accx); accy = fmaf(wB, bf_hi(gB), accy);
        accx = fmaf(wC, bf_lo(gC), accx); accy = fmaf(wC, bf_hi(gC), accy);
        accx = fmaf(wD, bf_lo(gD), accx); accy = fmaf(wD, bf_hi(gD), accy);
    }
    for (; k < kend; ++k) {
        int s = esrc[k];
        float w = dinv[s];
        unsigned g = Hb[(size_t)s * 64 + l];
        accx = fmaf(w, bf_lo(g), accx);
        accy = fmaf(w, bf_hi(g), accy);
    }
    float2 b = ((const float2*)bias)[l];
    float ox = fmaxf(fmaf(di, accx, b.x), 0.f);   // layer 1: ReLU
    float oy = fmaxf(fmaf(di, accy, b.y), 0.f);
    out[(size_t)wid * 64 + l] = pack_bf16(ox, oy);
}

// ---- aggregation, F=64, bf16 in, fp32 out (+bias); one wave per node ----
__global__ __launch_bounds__(256) void k_agg64(const unsigned short* __restrict__ Hb,
        const float* __restrict__ dinv, const int* __restrict__ rs,
        const int* __restrict__ esrc, const float* __restrict__ bias,
        float* __restrict__ out, int N) {
    int wid = (blockIdx.x * 256 + threadIdx.x) >> 6;
    if (wid >= N) return;
    int l = threadIdx.x & 63;
    float di = dinv[wid];
    float acc = di * __uint_as_float((unsigned)Hb[(size_t)wid * 64 + l] << 16);
    int k = rs[wid], kend = rs[wid + 1];
    for (; k + 4 <= kend; k += 4) {
        int sA = esrc[k], sB = esrc[k + 1], sC = esrc[k + 2], sD = esrc[k + 3];
        float wA = dinv[sA], wB = dinv[sB], wC = dinv[sC], wD = dinv[sD];
        float gA = __uint_as_float((unsigned)Hb[(size_t)sA * 64 + l] << 16);
        float gB = __uint_as_float((unsigned)Hb[(size_t)sB * 64 + l] << 16);
        float gC = __uint_as_float((unsigned)Hb[(size_t)sC * 64 + l] << 16);
        float gD = __uint_as_float((unsigned)Hb[(size_t)sD * 64 + l] << 16);
        acc = fmaf(wA, gA, acc); acc = fmaf(wB, gB, acc);
        acc = fmaf(wC, gC, acc); acc = fmaf(wD, gD, acc);
    }
    for (; k < kend; ++k) {
        int s = esrc[k];
        acc = fmaf(dinv[s], __uint_as_float((unsigned)Hb[(size_t)s * 64 + l] << 16), acc);
    }
    out[(size_t)wid * 64 + l] = fmaf(di, acc, bias[l]);
}

extern "C" void kernel_launch(void* const* d_in, const int* in_sizes, int n_in,
                              void* d_out, int out_size, void* d_ws, size_t ws_size,
                              hipStream_t stream) {
    const float* x  = (const float*)d_in[0];
    const void*  ei = d_in[1];
    const float* W1 = (const float*)d_in[2];
    const float* b1 = (const float*)d_in[3];
    const float* W2 = (const float*)d_in[4];
    const float* b2 = (const float*)d_in[5];

    const int HID = in_sizes[3];            // 128
    const int IN  = in_sizes[2] / HID;      // 128
    const int OUT = in_sizes[4] / HID;      // 64
    const int N   = in_sizes[0] / IN;       // 50000
    const int E   = in_sizes[1] / 2;        // 800000
    const int NBLK = (N + 1023) / 1024;
    const int NB   = (N + 127) >> BSHIFT;   // dst buckets (391)
    const int NC   = (E + CH - 1) / CH;     // chunks (391)

    char* p = (char*)d_ws;
    int* is32      = (int*)p;   p += 256;
    int* counts    = (int*)p;   p += align256((size_t)N * 4);
    size_t zero_bytes = (size_t)(p - (char*)d_ws);   // is32 + counts
    int* row_start = (int*)p;   p += align256((size_t)(N + 1) * 4);
    int* pos       = (int*)p;   p += align256((size_t)N * 4);
    int* bsum      = (int*)p;   p += align256((size_t)NBLK * 4);
    int* bexc      = (int*)p;   p += align256((size_t)NBLK * 4);
    int* chist     = (int*)p;   p += align256((size_t)NB * NC * 4);
    int* esrc      = (int*)p;   p += align256((size_t)E * 4);
    float* dinv    = (float*)p; p += align256((size_t)N * 4);
    unsigned short* w1t = (unsigned short*)p; p += align256((size_t)HID * IN * 2);
    unsigned short* w2t = (unsigned short*)p; p += align256((size_t)OUT * HID * 2);
    unsigned short* xb  = (unsigned short*)p; p += align256((size_t)N * IN * 2);
    // bbuf (E uint2, dead after k_fill2) overlays hb (N*HID bf16, written later)
    size_t hb_bytes = (size_t)N * HID * 2, bbuf_bytes = (size_t)E * 8;
    uint2* bbuf    = (uint2*)p;
    unsigned short* hb = (unsigned short*)p;
    p += align256(hb_bytes > bbuf_bytes ? hb_bytes : bbuf_bytes);
    unsigned short* h1b = (unsigned short*)p; p += align256((size_t)N * HID * 2);
    unsigned short* h2b = (unsigned short*)p; p += align256((size_t)N * OUT * 2);

    hipMemsetAsync(d_ws, 0, zero_bytes, stream);

    k_detect<<<4, 256, 0, stream>>>((const long long*)ei, 1024, is32);
    k_hist<<<NC, 256, 0, stream>>>(ei, E, is32, counts, chist, NB, NC);
    k_scan1<<<NBLK, 1024, 0, stream>>>(counts, row_start, bsum, N);
    k_scan2<<<1, 1024, 0, stream>>>(bsum, bexc, row_start, NBLK, N);
    k_scan3<<<(N + 255) / 256, 256, 0, stream>>>(row_start, pos, bexc, counts, dinv, N);
    k_hscan<<<(NB + 3) / 4, 256, 0, stream>>>(chist, row_start, NB, NC);
    k_bfill<<<NC, 256, 0, stream>>>(ei, E, is32, chist, bbuf, NB, NC);
    k_fill2<<<(E + 255) / 256, 256, 0, stream>>>(bbuf, E, pos, esrc);

    // bf16 conversions
    k_cvt8<<<((N * IN / 8) + 255) / 256, 256, 0, stream>>>(x, xb, N * IN / 8);
    k_cvt_w<<<(IN * HID + HID * OUT + 255) / 256, 256, 0, stream>>>(W1, W2, w1t, w2t,
                                                                     IN, HID, HID, OUT);

    // layer 1: hb = bf16(xb @ W1) ; h1b = bf16(relu(agg(hb) + b1))
    k_gemm_mfma<<<dim3((N + 63) / 64, HID / 64), 256, 0, stream>>>(xb, w1t, hb, N, HID);
    k_agg128<<<(N + 3) / 4, 256, 0, stream>>>((unsigned*)hb, dinv, row_start, esrc, b1,
                                              (unsigned*)h1b, N);

    // layer 2: h2b = bf16(h1b @ W2) ; out = agg(h2b) + b2
    k_gemm_mfma<<<dim3((N + 63) / 64, OUT / 64), 256, 0, stream>>>(h1b, w2t, h2b, N, OUT);
    k_agg64<<<(N + 3) / 4, 256, 0, stream>>>(h2b, dinv, row_start, esrc, b2, (float*)d_out, N);
}

// Round 7
// 246.630 us; speedup vs baseline: 3.2205x; 1.0396x over previous
//
#include <hip/hip_runtime.h>
#include <stdint.h>

typedef __attribute__((ext_vector_type(8))) short short8;
typedef __attribute__((ext_vector_type(4))) float floatx4;

static inline size_t align256(size_t x) { return (x + 255) & ~size_t(255); }

__device__ __forceinline__ unsigned short f2bf(float f) {
    unsigned u = __float_as_uint(f);
    u += 0x7fff + ((u >> 16) & 1);     // round-to-nearest-even
    return (unsigned short)(u >> 16);
}
__device__ __forceinline__ unsigned pack_bf16(float a, float b) {
    return (unsigned)f2bf(a) | ((unsigned)f2bf(b) << 16);
}
__device__ __forceinline__ float bf_lo(unsigned u) { return __uint_as_float(u << 16); }
__device__ __forceinline__ float bf_hi(unsigned u) { return __uint_as_float(u & 0xffff0000u); }

#define BSHIFT 7     // 128 nodes per dst-bucket
#define NBMAX 1024   // max buckets per LDS window
#define CH 2048      // edges per chunk (391 chunks at E=800k -> full occupancy)

// ---- per-block edge dtype self-detection (replaces k_detect kernel).
// int32 data read as int64 pairs: any nonzero high word => value > 2^31.
// P(all 256 sampled high words == 0 | int32 data) ~ (1/N)^256 ~ 0.
__device__ __forceinline__ bool detect_i32(const void* eidx, int E, int t) {
    const long long* e64 = (const long long*)eidx;
    int nchk = E < 256 ? E : 256;      // buffer holds >= E int64s in either dtype
    long long v = e64[t % nchk];
    int bad = (v < 0 || v > 0x7fffffffLL) ? 1 : 0;
    return __syncthreads_or(bad) != 0;
}

// ---- chunk histogram + global per-node counts (fused; one dst pass) ----
// chist layout: [bucket][chunk] (transposed for the per-bucket scan)
__global__ __launch_bounds__(256) void k_hist(const void* __restrict__ eidx, int E,
                                              int* __restrict__ counts,
                                              int* __restrict__ chist, int NB, int NC) {
    __shared__ int hist[NBMAX];
    const int t = threadIdx.x, c = blockIdx.x;
    const int e0 = c * CH;
    const int e1 = (e0 + CH < E) ? e0 + CH : E;
    const bool i32 = detect_i32(eidx, E, t);
    const int* e32 = (const int*)eidx;
    const long long* e64 = (const long long*)eidx;
    for (int b0 = 0; b0 < NB; b0 += NBMAX) {
        int bw = (NB - b0 < NBMAX) ? NB - b0 : NBMAX;
        for (int i = t; i < bw; i += 256) hist[i] = 0;
        __syncthreads();
        for (int e = e0 + t; e < e1; e += 256) {
            int d = i32 ? e32[(size_t)E + e] : (int)e64[(size_t)E + e];
            if (b0 == 0) atomicAdd(&counts[d], 1);   // 50k addresses: low contention
            int b = (d >> BSHIFT) - b0;
            if (b >= 0 && b < bw) atomicAdd(&hist[b], 1);
        }
        __syncthreads();
        for (int i = t; i < bw; i += 256) chist[(size_t)(b0 + i) * NC + c] = hist[i];
        __syncthreads();
    }
}

// ---- hierarchical exclusive scan of counts: pass 1 ----
__global__ __launch_bounds__(1024) void k_scan1(const int* __restrict__ counts,
                                                int* __restrict__ row_start,
                                                int* __restrict__ bsum, int N) {
    __shared__ int swt[16];
    __shared__ int swt2[16];
    const int t = threadIdx.x, lane = t & 63, w = t >> 6;
    int i = blockIdx.x * 1024 + t;
    int v = (i < N) ? counts[i] : 0;
    int incl = v;
    #pragma unroll
    for (int off = 1; off < 64; off <<= 1) {
        int nbr = __shfl_up(incl, off, 64);
        if (lane >= off) incl += nbr;
    }
    if (lane == 63) swt[w] = incl;
    __syncthreads();
    if (w == 0) {
        int wincl = (lane < 16) ? swt[lane] : 0;
        #pragma unroll
        for (int off = 1; off < 16; off <<= 1) {
            int nbr = __shfl_up(wincl, off, 64);
            if (lane >= off) wincl += nbr;
        }
        if (lane < 16) swt2[lane] = wincl;
    }
    __syncthreads();
    int excl = ((w == 0) ? 0 : swt2[w - 1]) + incl - v;
    if (i < N) row_start[i] = excl;
    if (t == 0) bsum[blockIdx.x] = swt2[15];
}

// ---- pass 2: single-block scan of block sums ----
__global__ __launch_bounds__(1024) void k_scan2(const int* __restrict__ bsum,
                                                int* __restrict__ bexc,
                                                int* __restrict__ row_start,
                                                int nblk, int N) {
    __shared__ int swt[16];
    __shared__ int swt2[16];
    const int t = threadIdx.x, lane = t & 63, w = t >> 6;
    int carry = 0;
    for (int base = 0; base < nblk; base += 1024) {
        int i = base + t;
        int v = (i < nblk) ? bsum[i] : 0;
        int incl = v;
        #pragma unroll
        for (int off = 1; off < 64; off <<= 1) {
            int nbr = __shfl_up(incl, off, 64);
            if (lane >= off) incl += nbr;
        }
        if (lane == 63) swt[w] = incl;
        __syncthreads();
        if (w == 0) {
            int wincl = (lane < 16) ? swt[lane] : 0;
            #pragma unroll
            for (int off = 1; off < 16; off <<= 1) {
                int nbr = __shfl_up(wincl, off, 64);
                if (lane >= off) wincl += nbr;
            }
            if (lane < 16) swt2[lane] = wincl;
        }
        __syncthreads();
        int excl = carry + ((w == 0) ? 0 : swt2[w - 1]) + incl - v;
        if (i < nblk) bexc[i] = excl;
        carry += swt2[15];
        __syncthreads();
    }
    if (t == 0) row_start[N] = carry;
}

// ---- pass 3: add block offsets; init pos; compute dinv ----
__global__ void k_scan3(int* __restrict__ row_start, int* __restrict__ pos,
                        const int* __restrict__ bexc, const int* __restrict__ counts,
                        float* __restrict__ dinv, int N) {
    int i = blockIdx.x * blockDim.x + threadIdx.x;
    if (i < N) {
        int r = row_start[i] + bexc[i >> 10];
        row_start[i] = r;
        pos[i] = r;
        dinv[i] = rsqrtf((float)counts[i] + 1.0f);
    }
}

// ---- per-bucket scan over chunks: chist[b][c] -> global base offsets.
//      One wave per bucket; seeded from row_start (buckets = contiguous dst). ----
__global__ __launch_bounds__(256) void k_hscan(int* __restrict__ chist,
                                               const int* __restrict__ row_start,
                                               int NB, int NC) {
    int b = blockIdx.x * 4 + (threadIdx.x >> 6);
    if (b >= NB) return;
    int lane = threadIdx.x & 63;
    int* row = chist + (size_t)b * NC;
    int carry = row_start[b << BSHIFT];
    for (int base = 0; base < NC; base += 64) {
        int i = base + lane;
        int v = (i < NC) ? row[i] : 0;
        int incl = v;
        #pragma unroll
        for (int off = 1; off < 64; off <<= 1) {
            int nbr = __shfl_up(incl, off, 64);
            if (lane >= off) incl += nbr;
        }
        if (i < NC) row[i] = carry + incl - v;
        carry += __shfl(incl, 63, 64);
    }
}

// ---- binned fill: deterministic base + LDS rank; NO global atomics ----
__global__ __launch_bounds__(256) void k_bfill(const void* __restrict__ eidx, int E,
                                               const int* __restrict__ chist,
                                               uint2* __restrict__ bbuf, int NB, int NC) {
    __shared__ int rank[NBMAX];
    __shared__ int base[NBMAX];
    const int t = threadIdx.x, c = blockIdx.x;
    const int e0 = c * CH;
    const int e1 = (e0 + CH < E) ? e0 + CH : E;
    const bool i32 = detect_i32(eidx, E, t);
    const int* e32 = (const int*)eidx;
    const long long* e64 = (const long long*)eidx;
    for (int b0 = 0; b0 < NB; b0 += NBMAX) {
        int bw = (NB - b0 < NBMAX) ? NB - b0 : NBMAX;
        for (int i = t; i < bw; i += 256) {
            rank[i] = 0;
            base[i] = chist[(size_t)(b0 + i) * NC + c];
        }
        __syncthreads();
        for (int e = e0 + t; e < e1; e += 256) {
            int s, d;
            if (i32) { s = e32[e]; d = e32[(size_t)E + e]; }
            else     { s = (int)e64[e]; d = (int)e64[(size_t)E + e]; }
            int b = (d >> BSHIFT) - b0;
            if (b >= 0 && b < bw) {
                int slot = base[b] + atomicAdd(&rank[b], 1);
                bbuf[slot] = make_uint2((unsigned)s, (unsigned)d);
            }
        }
        __syncthreads();
    }
}

// ---- fill pass B: scatter within bucket (~8KB window, cache-local) ----
__global__ void k_fill2(const uint2* __restrict__ bbuf, int E,
                        int* __restrict__ pos, int* __restrict__ esrc) {
    int i = blockIdx.x * blockDim.x + threadIdx.x;
    if (i >= E) return;
    uint2 sd = bbuf[i];
    int p = atomicAdd(&pos[sd.y], 1);
    esrc[p] = (int)sd.x;
}

// ---- fused conversions: x (fp32->bf16, 8/thread) + W1,W2 (transpose+cvt) ----
__global__ void k_cvt(const float* __restrict__ x, unsigned short* __restrict__ xb, int n8,
                      const float* __restrict__ W1, const float* __restrict__ W2,
                      unsigned short* __restrict__ w1t, unsigned short* __restrict__ w2t,
                      int K1, int M1, int K2, int M2) {
    int idx = blockIdx.x * blockDim.x + threadIdx.x;
    if (idx < n8) {
        float4 a = ((const float4*)x)[2 * idx];
        float4 b = ((const float4*)x)[2 * idx + 1];
        uint4 o;
        o.x = pack_bf16(a.x, a.y); o.y = pack_bf16(a.z, a.w);
        o.z = pack_bf16(b.x, b.y); o.w = pack_bf16(b.z, b.w);
        ((uint4*)xb)[idx] = o;
        return;
    }
    int j = idx - n8;
    if (j < K1 * M1) {
        int k = j / M1, n = j % M1;
        w1t[(size_t)n * K1 + k] = f2bf(W1[j]);
    } else if (j - K1 * M1 < K2 * M2) {
        int j2 = j - K1 * M1;
        int k = j2 / M2, n = j2 % M2;
        w2t[(size_t)n * K2 + k] = f2bf(W2[j2]);
    }
}

// ---- bf16 MFMA GEMM with dinv-folded epilogue:
//      C[row] = bf16( dinv[row] * (A[row] @ Bt^T) )  -- "hs" rows, so the
//      aggregation becomes a pure gather-sum (no per-edge weights). ----
__global__ __launch_bounds__(256, 4) void k_gemm_mfma(
        const unsigned short* __restrict__ A,
        const unsigned short* __restrict__ Bt,
        const float* __restrict__ dinv,
        unsigned short* __restrict__ C,
        int N, int M) {
    constexpr int LD = 136;               // 128 + 8 u16 pad: 2-way LDS aliasing = free
    __shared__ unsigned short As[64 * LD];
    __shared__ unsigned short Bs[64 * LD];
    const int tid = threadIdx.x;
    const int wave = tid >> 6, lane = tid & 63;
    const int q = lane >> 4, tm = lane & 15;
    const int row0 = blockIdx.x * 64;
    const int c0 = blockIdx.y * 64;

    {
        const uint4* Ag = (const uint4*)A;
        const uint4* Bg = (const uint4*)Bt;
        #pragma unroll
        for (int it = 0; it < 4; ++it) {
            int i = tid + it * 256;
            int r = i >> 4, o = i & 15;
            int row = row0 + r;
            uint4 v = make_uint4(0, 0, 0, 0);
            if (row < N) v = Ag[(size_t)row * 16 + o];
            *(uint4*)&As[r * LD + o * 8] = v;
            *(uint4*)&Bs[r * LD + o * 8] = Bg[(size_t)(c0 + r) * 16 + o];
        }
    }
    __syncthreads();

    floatx4 acc[4];
    #pragma unroll
    for (int g = 0; g < 4; ++g) acc[g] = (floatx4){0.f, 0.f, 0.f, 0.f};

    const int arow = wave * 16 + tm;
    #pragma unroll
    for (int kc = 0; kc < 4; ++kc) {
        short8 af = *(const short8*)&As[arow * LD + kc * 32 + q * 8];
        #pragma unroll
        for (int g = 0; g < 4; ++g) {
            short8 bf = *(const short8*)&Bs[(g * 16 + tm) * LD + kc * 32 + q * 8];
            acc[g] = __builtin_amdgcn_mfma_f32_16x16x32_bf16(af, bf, acc[g], 0, 0, 0);
        }
    }

    float dv[4];
    #pragma unroll
    for (int r = 0; r < 4; ++r) {
        int row = row0 + wave * 16 + q * 4 + r;
        dv[r] = (row < N) ? dinv[row] : 0.f;
    }
    #pragma unroll
    for (int g = 0; g < 4; ++g) {
        #pragma unroll
        for (int r = 0; r < 4; ++r) {
            int row = row0 + wave * 16 + q * 4 + r;
            if (row < N) C[(size_t)row * M + c0 + g * 16 + tm] = f2bf(dv[r] * acc[g][r]);
        }
    }
}

// ---- aggregation, F=128: pure gather-sum of pre-scaled rows; 8-deep pipeline ----
__global__ __launch_bounds__(256) void k_agg128(const unsigned* __restrict__ Hb,
        const float* __restrict__ dinv, const int* __restrict__ rs,
        const int* __restrict__ esrc, const float* __restrict__ bias,
        unsigned* __restrict__ out, int N) {
    int wid = (blockIdx.x * 256 + threadIdx.x) >> 6;
    if (wid >= N) return;
    int l = threadIdx.x & 63;
    float di = dinv[wid];
    unsigned a = Hb[(size_t)wid * 64 + l];         // self row (already dinv-scaled)
    float accx = bf_lo(a), accy = bf_hi(a);
    int k = rs[wid], kend = rs[wid + 1];
    for (; k + 8 <= kend; k += 8) {
        int s[8];
        #pragma unroll
        for (int j = 0; j < 8; ++j) s[j] = esrc[k + j];   // wave-uniform -> scalar loads
        unsigned g[8];
        #pragma unroll
        for (int j = 0; j < 8; ++j) g[j] = Hb[(size_t)s[j] * 64 + l];
        #pragma unroll
        for (int j = 0; j < 8; ++j) { accx += bf_lo(g[j]); accy += bf_hi(g[j]); }
    }
    if (k + 4 <= kend) {
        int s[4];
        #pragma unroll
        for (int j = 0; j < 4; ++j) s[j] = esrc[k + j];
        unsigned g[4];
        #pragma unroll
        for (int j = 0; j < 4; ++j) g[j] = Hb[(size_t)s[j] * 64 + l];
        #pragma unroll
        for (int j = 0; j < 4; ++j) { accx += bf_lo(g[j]); accy += bf_hi(g[j]); }
        k += 4;
    }
    for (; k < kend; ++k) {
        unsigned g = Hb[(size_t)esrc[k] * 64 + l];
        accx += bf_lo(g); accy += bf_hi(g);
    }
    float2 b = ((const float2*)bias)[l];
    float ox = fmaxf(fmaf(di, accx, b.x), 0.f);   // layer 1: ReLU
    float oy = fmaxf(fmaf(di, accy, b.y), 0.f);
    out[(size_t)wid * 64 + l] = pack_bf16(ox, oy);
}

// ---- aggregation, F=64: pure gather-sum; fp32 out (+bias) ----
__global__ __launch_bounds__(256) void k_agg64(const unsigned short* __restrict__ Hb,
        const float* __restrict__ dinv, const int* __restrict__ rs,
        const int* __restrict__ esrc, const float* __restrict__ bias,
        float* __restrict__ out, int N) {
    int wid = (blockIdx.x * 256 + threadIdx.x) >> 6;
    if (wid >= N) return;
    int l = threadIdx.x & 63;
    float di = dinv[wid];
    float acc = __uint_as_float((unsigned)Hb[(size_t)wid * 64 + l] << 16);
    int k = rs[wid], kend = rs[wid + 1];
    for (; k + 8 <= kend; k += 8) {
        int s[8];
        #pragma unroll
        for (int j = 0; j < 8; ++j) s[j] = esrc[k + j];
        unsigned short g[8];
        #pragma unroll
        for (int j = 0; j < 8; ++j) g[j] = Hb[(size_t)s[j] * 64 + l];
        #pragma unroll
        for (int j = 0; j < 8; ++j) acc += __uint_as_float((unsigned)g[j] << 16);
    }
    if (k + 4 <= kend) {
        int s[4];
        #pragma unroll
        for (int j = 0; j < 4; ++j) s[j] = esrc[k + j];
        unsigned short g[4];
        #pragma unroll
        for (int j = 0; j < 4; ++j) g[j] = Hb[(size_t)s[j] * 64 + l];
        #pragma unroll
        for (int j = 0; j < 4; ++j) acc += __uint_as_float((unsigned)g[j] << 16);
        k += 4;
    }
    for (; k < kend; ++k)
        acc += __uint_as_float((unsigned)Hb[(size_t)esrc[k] * 64 + l] << 16);
    out[(size_t)wid * 64 + l] = fmaf(di, acc, bias[l]);
}

extern "C" void kernel_launch(void* const* d_in, const int* in_sizes, int n_in,
                              void* d_out, int out_size, void* d_ws, size_t ws_size,
                              hipStream_t stream) {
    const float* x  = (const float*)d_in[0];
    const void*  ei = d_in[1];
    const float* W1 = (const float*)d_in[2];
    const float* b1 = (const float*)d_in[3];
    const float* W2 = (const float*)d_in[4];
    const float* b2 = (const float*)d_in[5];

    const int HID = in_sizes[3];            // 128
    const int IN  = in_sizes[2] / HID;      // 128
    const int OUT = in_sizes[4] / HID;      // 64
    const int N   = in_sizes[0] / IN;       // 50000
    const int E   = in_sizes[1] / 2;        // 800000
    const int NBLK = (N + 1023) / 1024;
    const int NB   = (N + 127) >> BSHIFT;   // dst buckets (391)
    const int NC   = (E + CH - 1) / CH;     // chunks (391)

    char* p = (char*)d_ws;
    int* counts    = (int*)p;   p += align256((size_t)N * 4);
    int* row_start = (int*)p;   p += align256((size_t)(N + 1) * 4);
    int* pos       = (int*)p;   p += align256((size_t)N * 4);
    int* bsum      = (int*)p;   p += align256((size_t)NBLK * 4);
    int* bexc      = (int*)p;   p += align256((size_t)NBLK * 4);
    int* chist     = (int*)p;   p += align256((size_t)NB * NC * 4);
    int* esrc      = (int*)p;   p += align256((size_t)E * 4);
    float* dinv    = (float*)p; p += align256((size_t)N * 4);
    unsigned short* w1t = (unsigned short*)p; p += align256((size_t)HID * IN * 2);
    unsigned short* w2t = (unsigned short*)p; p += align256((size_t)OUT * HID * 2);
    unsigned short* xb  = (unsigned short*)p; p += align256((size_t)N * IN * 2);
    // bbuf (E uint2, dead after k_fill2) overlays hb (N*HID bf16, written later)
    size_t hb_bytes = (size_t)N * HID * 2, bbuf_bytes = (size_t)E * 8;
    uint2* bbuf    = (uint2*)p;
    unsigned short* hb = (unsigned short*)p;
    p += align256(hb_bytes > bbuf_bytes ? hb_bytes : bbuf_bytes);
    unsigned short* h1b = (unsigned short*)p; p += align256((size_t)N * HID * 2);
    unsigned short* h2b = (unsigned short*)p; p += align256((size_t)N * OUT * 2);

    hipMemsetAsync(counts, 0, (size_t)N * 4, stream);

    k_hist<<<NC, 256, 0, stream>>>(ei, E, counts, chist, NB, NC);
    k_scan1<<<NBLK, 1024, 0, stream>>>(counts, row_start, bsum, N);
    k_scan2<<<1, 1024, 0, stream>>>(bsum, bexc, row_start, NBLK, N);
    k_scan3<<<(N + 255) / 256, 256, 0, stream>>>(row_start, pos, bexc, counts, dinv, N);
    k_hscan<<<(NB + 3) / 4, 256, 0, stream>>>(chist, row_start, NB, NC);
    k_bfill<<<NC, 256, 0, stream>>>(ei, E, chist, bbuf, NB, NC);
    k_fill2<<<(E + 255) / 256, 256, 0, stream>>>(bbuf, E, pos, esrc);

    const int n8 = N * IN / 8;
    k_cvt<<<(n8 + IN * HID + HID * OUT + 255) / 256, 256, 0, stream>>>(
        x, xb, n8, W1, W2, w1t, w2t, IN, HID, HID, OUT);

    // layer 1: hb = bf16(dinv * (xb @ W1)) ; h1b = bf16(relu(dinv*sum + b1))
    k_gemm_mfma<<<dim3((N + 63) / 64, HID / 64), 256, 0, stream>>>(xb, w1t, dinv, hb, N, HID);
    k_agg128<<<(N + 3) / 4, 256, 0, stream>>>((unsigned*)hb, dinv, row_start, esrc, b1,
                                              (unsigned*)h1b, N);

    // layer 2: h2b = bf16(dinv * (h1b @ W2)) ; out = dinv*sum + b2
    k_gemm_mfma<<<dim3((N + 63) / 64, OUT / 64), 256, 0, stream>>>(h1b, w2t, dinv, h2b, N, OUT);
    k_agg64<<<(N + 3) / 4, 256, 0, stream>>>(h2b, dinv, row_start, esrc, b2, (float*)d_out, N);
}